// Round 1
// 967.505 us; speedup vs baseline: 1.2490x; 1.2490x over previous
//
#include <hip/hip_runtime.h>

#define N_NODE   10000
#define E_EDGE   320000
#define E_LINKN  1280000
#define DIM      128
#define EFEAT    24
#define SEQLEN   64

#define SCAN_CHUNK 4096   // elements per block in hierarchical scan

// ---------------- workspace layout (bytes) ----------------
// zeroed region first (single memset): histograms + cursors for both CSR builds
static const size_t OFF_DEGN  = 0;                                    // 10240 i32
static const size_t OFF_CURN  = OFF_DEGN  + 10240*4;                  // 10240 i32
static const size_t OFF_DEGL  = OFF_CURN  + 10240*4;                  // E_EDGE i32
static const size_t OFF_CURL  = OFF_DEGL  + (size_t)E_EDGE*4;         // E_EDGE i32
static const size_t ZERO_BYTES= OFF_CURL  + (size_t)E_EDGE*4;
// non-zeroed:
static const size_t OFF_CONST = ZERO_BYTES;                           // 512 f32 (Ball 432 + cvec 24)
static const size_t OFF_V0    = OFF_CONST + 512*4;                    // [E,6]  f32
static const size_t OFF_V12   = OFF_V0    + (size_t)E_EDGE*6*4;       // [E,12] f32
static const size_t OFF_PW    = OFF_V12   + (size_t)E_EDGE*12*4;      // [E,12] f32
static const size_t OFF_WSUM  = OFF_PW    + (size_t)E_EDGE*12*4;      // [E]    f32
static const size_t OFF_STARTN= OFF_WSUM  + (size_t)E_EDGE*4;         // 10304 i32 (uses 10001)
static const size_t OFF_SRCSN = OFF_STARTN+ 10304*4;                  // [E] i32 (CSR-sorted src node)
static const size_t OFF_POSN  = OFF_SRCSN + (size_t)E_EDGE*4;         // [E] i32 (edge -> CSR slot)
static const size_t OFF_WKS   = OFF_POSN  + (size_t)E_EDGE*4;         // [E,3] f32 (CSR-sorted wk)
static const size_t OFF_STARTL= OFF_WKS   + (size_t)E_EDGE*3*4;       // E_EDGE+64 i32
static const size_t OFF_SRCSL = OFF_STARTL+ ((size_t)E_EDGE+64)*4;    // [E_LINK] i32 (sorted src)
static const size_t OFF_WL    = OFF_SRCSL + (size_t)E_LINKN*4;        // [E_LINK] f32 (sorted w)
static const size_t OFF_HENT  = OFF_WL    + (size_t)E_LINKN*4;        // [N,128]
static const size_t OFF_HA    = OFF_HENT  + (size_t)N_NODE*DIM*4;     // [N,128]
static const size_t OFF_HB    = OFF_HA    + (size_t)N_NODE*DIM*4;     // [N,128]
static const size_t OFF_PARTN = OFF_HB    + (size_t)N_NODE*DIM*4;     // 512 i32 (partials+offs, node)
static const size_t OFF_PARTL = OFF_PARTN + 512*4;                    // 512 i32 (partials+offs, link)

// ---------------- tiny-constant precompute ----------------
// 3 blocks, one per Laguerre term k. Each block:
//   M_k[r][d] (128x128, LDS, stride 129 to dodge bank conflicts) from Whl (coalesced),
//   A_k[r][j] = sum_d M_k[r][d] * Wec[d*6+j]         (768 outputs, LDS->LDS),
//   Ball[i*18 + k*6 + j] = sum_r Wstart[i*128+r]*A_k  (144 outputs),
//   cvec[k*6+j] = sum_r bstart[r]*A_k; block 0 also cvec[18+j] = bec[j] + bhl@Wec.
// Same inner-loop summation order as the previous (verified) version.
__global__ void consts_kernel(const float* __restrict__ Wstart, const float* __restrict__ bstart,
                              const float* __restrict__ Whl,    const float* __restrict__ bhl,
                              const float* __restrict__ Wec,    const float* __restrict__ bec,
                              float* __restrict__ Ball, float* __restrict__ cvec) {
    __shared__ float M[128*129];   // 66048 B
    __shared__ float sWec[768];
    __shared__ float A[768];       // A[r*6 + j] for this block's k
    int k = blockIdx.x;
    int t = threadIdx.x;

    for (int i = t; i < 768; i += 256) sWec[i] = Wec[i];

    const float* w0 = Whl;
    const float* w1 = Whl + 16384;
    const float* w2 = Whl + 32768;
    for (int idx = t; idx < 16384; idx += 256) {
        int r = idx >> 7, d = idx & 127;
        float m;
        if (k == 0)      m = w0[idx] + w1[idx] + w2[idx];
        else if (k == 1) m = -(w1[idx] + 2.f*w2[idx]);
        else             m = 0.5f * w2[idx];
        M[r*129 + d] = m;
    }
    __syncthreads();

    for (int idx = t; idx < 768; idx += 256) {
        int r = idx / 6, j = idx % 6;
        float s = 0.f;
        for (int d = 0; d < 128; d++) s += M[r*129 + d] * sWec[d*6 + j];
        A[idx] = s;
    }
    __syncthreads();

    if (t < 144) {
        int i = t / 6, j = t % 6;
        float s = 0.f;
        for (int r = 0; r < 128; r++) s += Wstart[i*128 + r] * A[r*6 + j];
        Ball[i*18 + k*6 + j] = s;
    } else if (t < 150) {
        int j = t - 144;
        float s = 0.f;
        for (int r = 0; r < 128; r++) s += bstart[r] * A[r*6 + j];
        cvec[k*6 + j] = s;
    } else if (k == 0 && t >= 160 && t < 166) {
        int j = t - 160;
        float s = bec[j];
        for (int d = 0; d < 128; d++) s += bhl[d] * sWec[d*6 + j];
        cvec[18 + j] = s;
    }
}

// V = x_link @ Ball : V0 = cols 0..5, V12 = cols 6..17
__global__ void v_kernel(const float* __restrict__ x, const float* __restrict__ Ball,
                         float* __restrict__ V0, float* __restrict__ V12) {
    __shared__ float sB[432];
    for (int i = threadIdx.x; i < 432; i += blockDim.x) sB[i] = Ball[i];
    __syncthreads();
    int e = blockIdx.x * blockDim.x + threadIdx.x;
    if (e >= E_EDGE) return;
    float xr[24];
    const float4* xp = (const float4*)(x + (size_t)e*24);
#pragma unroll
    for (int q = 0; q < 6; q++) {
        float4 v = xp[q];
        xr[4*q+0] = v.x; xr[4*q+1] = v.y; xr[4*q+2] = v.z; xr[4*q+3] = v.w;
    }
    float o[18];
#pragma unroll
    for (int j = 0; j < 18; j++) o[j] = 0.f;
#pragma unroll
    for (int i = 0; i < 24; i++) {
        float xv = xr[i];
#pragma unroll
        for (int j = 0; j < 18; j++) o[j] += xv * sB[i*18 + j];
    }
#pragma unroll
    for (int j = 0; j < 6; j++)  V0[(size_t)e*6 + j]  = o[j];
#pragma unroll
    for (int j = 0; j < 12; j++) V12[(size_t)e*12 + j] = o[6 + j];
}

// ---------------- CSR builds ----------------
__global__ void hist_kernel(const int* __restrict__ dst, int* __restrict__ deg, int n) {
    int e = blockIdx.x * blockDim.x + threadIdx.x;
    if (e < n) atomicAdd(deg + dst[e], 1);
}

// ---- hierarchical exclusive scan: phase 1 (per-block sums, coalesced) ----
__global__ void partial_kernel(const int* __restrict__ deg, int* __restrict__ partials, int n) {
    __shared__ int red[256];
    int b = blockIdx.x, t = threadIdx.x;
    int base = b * SCAN_CHUNK;
    int s = 0;
    for (int i = t; i < SCAN_CHUNK; i += 256) {
        int idx = base + i;
        if (idx < n) s += deg[idx];
    }
    red[t] = s;
    __syncthreads();
    for (int off = 128; off > 0; off >>= 1) {
        if (t < off) red[t] += red[t + off];
        __syncthreads();
    }
    if (t == 0) partials[b] = red[0];
}

// ---- phase 2: scan of block partials (nb <= 256), writes offs[] and start[n]=total ----
__global__ void scan_partials_kernel(const int* __restrict__ partials, int* __restrict__ offs,
                                     int* __restrict__ start, int nb, int n) {
    __shared__ int a[256];
    int t = threadIdx.x;
    a[t] = (t < nb) ? partials[t] : 0;
    __syncthreads();
    for (int off = 1; off < 256; off <<= 1) {
        int v = (t >= off) ? a[t - off] : 0;
        __syncthreads();
        a[t] += v;
        __syncthreads();
    }
    offs[t] = (t == 0) ? 0 : a[t - 1];
    if (t == 255) start[n] = a[nb - 1];
}

// ---- phase 3: per-block exclusive scan + global offset, coalesced in/out ----
__global__ void scan_block_kernel(const int* __restrict__ deg, const int* __restrict__ offs,
                                  int* __restrict__ start, int n) {
    __shared__ int s[SCAN_CHUNK];
    __shared__ int tsum[256];
    int b = blockIdx.x, t = threadIdx.x;
    int base = b * SCAN_CHUNK;
    for (int i = t; i < SCAN_CHUNK; i += 256) {
        int idx = base + i;
        s[i] = (idx < n) ? deg[idx] : 0;
    }
    __syncthreads();
    // per-thread serial sum of its 16 contiguous elements
    int lo = t * 16;
    int mysum = 0;
#pragma unroll
    for (int j = 0; j < 16; j++) mysum += s[lo + j];
    tsum[t] = mysum;
    __syncthreads();
    for (int off = 1; off < 256; off <<= 1) {
        int v = (t >= off) ? tsum[t - off] : 0;
        __syncthreads();
        tsum[t] += v;
        __syncthreads();
    }
    int run = offs[b] + ((t == 0) ? 0 : tsum[t - 1]);
#pragma unroll
    for (int j = 0; j < 16; j++) {
        int v = s[lo + j];
        s[lo + j] = run;
        run += v;
    }
    __syncthreads();
    for (int i = t; i < SCAN_CHUNK; i += 256) {
        int idx = base + i;
        if (idx < n) start[idx] = s[i];
    }
}

// node-graph fill: store sorted src and edge->slot map (wk gets written sorted later)
__global__ void fill_n_kernel(const int* __restrict__ srcn, const int* __restrict__ dstn,
                              const int* __restrict__ start, int* __restrict__ cursor,
                              int* __restrict__ srcs_srt, int* __restrict__ pos) {
    int e = blockIdx.x * blockDim.x + threadIdx.x;
    if (e >= E_EDGE) return;
    int d = dstn[e];
    int p = start[d] + atomicAdd(cursor + d, 1);
    srcs_srt[p] = srcn[e];
    pos[e] = p;
}

// link-graph fill: store packed (src, w) in CSR order
__global__ void fill_l_kernel(const int* __restrict__ srcl, const int* __restrict__ dstl,
                              const float* __restrict__ ew,
                              const int* __restrict__ start, int* __restrict__ cursor,
                              int* __restrict__ srcs_srt, float* __restrict__ w_srt) {
    int e = blockIdx.x * blockDim.x + threadIdx.x;
    if (e >= E_LINKN) return;
    int d = dstl[e];
    int p = start[d] + atomicAdd(cursor + d, 1);
    srcs_srt[p] = srcl[e];
    w_srt[p] = ew[e];
}

// PW[e] = sum_links w*V12[src], wsum[e] = sum w   (pure gather, no atomics)
__global__ void prop1_gather(const float* __restrict__ V12, const int* __restrict__ startl,
                             const int* __restrict__ srcsl, const float* __restrict__ wl,
                             float* __restrict__ PW, float* __restrict__ wsum) {
    int e = blockIdx.x * blockDim.x + threadIdx.x;
    if (e >= E_EDGE) return;
    int s0 = startl[e], s1 = startl[e + 1];
    float acc[12];
#pragma unroll
    for (int j = 0; j < 12; j++) acc[j] = 0.f;
    float ws = 0.f;
    for (int j = s0; j < s1; j++) {
        int s = srcsl[j];
        float w = wl[j];
        const float4* vp = (const float4*)(V12 + (size_t)s*12);
#pragma unroll
        for (int q = 0; q < 3; q++) {
            float4 v = vp[q];
            acc[4*q+0] += w*v.x; acc[4*q+1] += w*v.y;
            acc[4*q+2] += w*v.z; acc[4*q+3] += w*v.w;
        }
        ws += w;
    }
    float4* pw = (float4*)(PW + (size_t)e*12);
#pragma unroll
    for (int q = 0; q < 3; q++)
        pw[q] = make_float4(acc[4*q+0], acc[4*q+1], acc[4*q+2], acc[4*q+3]);
    wsum[e] = ws;
}

// fused: gather P2/wsum2, combine with V0 + PW[:, :6] + wsum, sigmoid -> wk (CSR-sorted write)
__global__ void prop2score_kernel(const float* __restrict__ PW, const float* __restrict__ wsum,
                                  const int* __restrict__ startl, const int* __restrict__ srcsl,
                                  const float* __restrict__ wl, const float* __restrict__ V0,
                                  const float* __restrict__ cvec, const int* __restrict__ posn,
                                  float* __restrict__ wks) {
    __shared__ float sc[24];
    if (threadIdx.x < 24) sc[threadIdx.x] = cvec[threadIdx.x];
    __syncthreads();
    int e = blockIdx.x * blockDim.x + threadIdx.x;
    if (e >= E_EDGE) return;
    int s0 = startl[e], s1 = startl[e + 1];
    float p2[6];
#pragma unroll
    for (int j = 0; j < 6; j++) p2[j] = 0.f;
    float ws2 = 0.f;
    for (int j = s0; j < s1; j++) {
        int s = srcsl[j];
        float w = wl[j];
        const float2* pv = (const float2*)(PW + (size_t)s*12 + 6);
#pragma unroll
        for (int q = 0; q < 3; q++) {
            float2 v = pv[q];
            p2[2*q+0] += w*v.x; p2[2*q+1] += w*v.y;
        }
        ws2 += w * wsum[s];
    }
    float ws1 = wsum[e];
    float S[6];
#pragma unroll
    for (int j = 0; j < 6; j++)
        S[j] = V0[(size_t)e*6 + j] + PW[(size_t)e*12 + j] + p2[j]
             + ws1*sc[6 + j] + ws2*sc[12 + j] + sc[j] + sc[18 + j];
    int p = posn[e];
#pragma unroll
    for (int k = 0; k < 3; k++)
        wks[(size_t)p*3 + k] = 1.f / (1.f + __expf(S[2*k+1] - S[2*k]));
}

// ---------------- temporal projection ----------------
__global__ void temporal_kernel(const float4* __restrict__ h_entity, const float* __restrict__ Wt,
                                const float* __restrict__ bt, float4* __restrict__ h_ent) {
    __shared__ float sw[SEQLEN];
    if (threadIdx.x < SEQLEN) sw[threadIdx.x] = Wt[threadIdx.x];
    __syncthreads();
    int i = blockIdx.x * blockDim.x + threadIdx.x;            // over N*D/4 = 320000
    if (i >= N_NODE*DIM/4) return;
    float b = bt[0];
    float4 acc = make_float4(b, b, b, b);
#pragma unroll 8
    for (int t = 0; t < SEQLEN; t++) {
        float4 v = h_entity[(size_t)t * (N_NODE*DIM/4) + i];
        float w = sw[t];
        acc.x += w*v.x; acc.y += w*v.y; acc.z += w*v.z; acc.w += w*v.w;
    }
    h_ent[i] = acc;
}

// ---------------- fused GCN hop: h_next = P_k(h_cur); out (+)= h_next @ G_k (+ b_gcn if first)
__global__ void hop_kernel(const float* __restrict__ h_cur, float* __restrict__ h_next,
                           float* __restrict__ out,
                           const int* __restrict__ startn, const int* __restrict__ srcs_srt,
                           const float* __restrict__ wks, int k,
                           const float* __restrict__ G, const float* __restrict__ bgcn, int first) {
    int node = blockIdx.x;
    int tid  = threadIdx.x;          // 128
    int s0 = startn[node], s1 = startn[node + 1];
    float acc = 0.f;
    for (int j = s0; j < s1; j++) {
        float w = wks[(size_t)j*3 + k];
        int sn = srcs_srt[j];
        acc += w * h_cur[(size_t)sn*DIM + tid];
    }
    h_next[(size_t)node*DIM + tid] = acc;
    __shared__ float hrow[DIM];
    hrow[tid] = acc;
    __syncthreads();
    float o = first ? bgcn[tid] : out[(size_t)node*DIM + tid];
#pragma unroll 8
    for (int d = 0; d < DIM; d++) o += hrow[d] * G[d*DIM + tid];
    out[(size_t)node*DIM + tid] = o;
}

extern "C" void kernel_launch(void* const* d_in, const int* in_sizes, int n_in,
                              void* d_out, int out_size, void* d_ws, size_t ws_size,
                              hipStream_t stream) {
    const float* h_entity = (const float*)d_in[0];
    const float* x_link   = (const float*)d_in[1];
    const float* ewl      = (const float*)d_in[2];
    const int*   eil      = (const int*)d_in[3];
    const int*   ein      = (const int*)d_in[4];
    const float* Wstart   = (const float*)d_in[5];
    const float* bstart   = (const float*)d_in[6];
    const float* Whl      = (const float*)d_in[7];
    const float* bhl      = (const float*)d_in[8];
    const float* Wec      = (const float*)d_in[9];
    const float* bec      = (const float*)d_in[10];
    const float* Wt       = (const float*)d_in[11];
    const float* bt       = (const float*)d_in[12];
    const float* Wgcn     = (const float*)d_in[13];
    const float* bgcn     = (const float*)d_in[14];
    float* out = (float*)d_out;
    char*  ws  = (char*)d_ws;

    const int* srcl = eil;
    const int* dstl = eil + E_LINKN;
    const int* srcn = ein;
    const int* dstn = ein + E_EDGE;

    int*   degn  = (int*)  (ws + OFF_DEGN);
    int*   curn  = (int*)  (ws + OFF_CURN);
    int*   degl  = (int*)  (ws + OFF_DEGL);
    int*   curl  = (int*)  (ws + OFF_CURL);
    float* Ball  = (float*)(ws + OFF_CONST);
    float* cvec  = Ball + 432;
    float* V0    = (float*)(ws + OFF_V0);
    float* V12   = (float*)(ws + OFF_V12);
    float* PW    = (float*)(ws + OFF_PW);
    float* wsum  = (float*)(ws + OFF_WSUM);
    int*   startn= (int*)  (ws + OFF_STARTN);
    int*   srcsn = (int*)  (ws + OFF_SRCSN);
    int*   posn  = (int*)  (ws + OFF_POSN);
    float* wks   = (float*)(ws + OFF_WKS);
    int*   startl= (int*)  (ws + OFF_STARTL);
    int*   srcsl = (int*)  (ws + OFF_SRCSL);
    float* wl    = (float*)(ws + OFF_WL);
    float* h_ent = (float*)(ws + OFF_HENT);
    float* h_a   = (float*)(ws + OFF_HA);
    float* h_b   = (float*)(ws + OFF_HB);
    int*   partn = (int*)  (ws + OFF_PARTN);  // partials, offs = partn+256
    int*   partl = (int*)  (ws + OFF_PARTL);

    const int nbN = (N_NODE + SCAN_CHUNK - 1) / SCAN_CHUNK;   // 3
    const int nbL = (E_EDGE + SCAN_CHUNK - 1) / SCAN_CHUNK;   // 79

    hipMemsetAsync(ws, 0, ZERO_BYTES, stream);

    consts_kernel<<<3, 256, 0, stream>>>(Wstart, bstart, Whl, bhl, Wec, bec, Ball, cvec);
    v_kernel<<<(E_EDGE + 255)/256, 256, 0, stream>>>(x_link, Ball, V0, V12);

    // CSR builds (hist -> hierarchical scan -> fill)
    hist_kernel<<<(E_EDGE + 255)/256, 256, 0, stream>>>(dstn, degn, E_EDGE);
    hist_kernel<<<(E_LINKN + 255)/256, 256, 0, stream>>>(dstl, degl, E_LINKN);

    partial_kernel<<<nbN, 256, 0, stream>>>(degn, partn, N_NODE);
    scan_partials_kernel<<<1, 256, 0, stream>>>(partn, partn + 256, startn, nbN, N_NODE);
    scan_block_kernel<<<nbN, 256, 0, stream>>>(degn, partn + 256, startn, N_NODE);

    partial_kernel<<<nbL, 256, 0, stream>>>(degl, partl, E_EDGE);
    scan_partials_kernel<<<1, 256, 0, stream>>>(partl, partl + 256, startl, nbL, E_EDGE);
    scan_block_kernel<<<nbL, 256, 0, stream>>>(degl, partl + 256, startl, E_EDGE);

    fill_n_kernel<<<(E_EDGE + 255)/256, 256, 0, stream>>>(srcn, dstn, startn, curn, srcsn, posn);
    fill_l_kernel<<<(E_LINKN + 255)/256, 256, 0, stream>>>(srcl, dstl, ewl, startl, curl, srcsl, wl);

    // link-graph propagates (gather)
    prop1_gather<<<(E_EDGE + 255)/256, 256, 0, stream>>>(V12, startl, srcsl, wl, PW, wsum);
    prop2score_kernel<<<(E_EDGE + 255)/256, 256, 0, stream>>>(PW, wsum, startl, srcsl, wl,
                                                             V0, cvec, posn, wks);

    temporal_kernel<<<(N_NODE*DIM/4 + 255)/256, 256, 0, stream>>>(
        (const float4*)h_entity, Wt, bt, (float4*)h_ent);

    hop_kernel<<<N_NODE, DIM, 0, stream>>>(h_ent, h_a, out, startn, srcsn, wks, 0,
                                           Wgcn + 0*16384, bgcn, 1);
    hop_kernel<<<N_NODE, DIM, 0, stream>>>(h_a, h_b, out, startn, srcsn, wks, 1,
                                           Wgcn + 1*16384, bgcn, 0);
    hop_kernel<<<N_NODE, DIM, 0, stream>>>(h_b, h_ent, out, startn, srcsn, wks, 2,
                                           Wgcn + 2*16384, bgcn, 0);
}

// Round 2
// 953.682 us; speedup vs baseline: 1.2671x; 1.0145x over previous
//
#include <hip/hip_runtime.h>

#define N_NODE   10000
#define E_EDGE   320000
#define E_LINKN  1280000
#define DIM      128
#define EFEAT    24
#define SEQLEN   64

#define SCAN_CHUNK 4096   // elements per block in hierarchical scan

// ---------------- workspace layout (bytes) ----------------
// zeroed region first (single memset): histograms + cursors for both CSR builds
static const size_t OFF_DEGN  = 0;                                    // 10240 i32
static const size_t OFF_CURN  = OFF_DEGN  + 10240*4;                  // 10240 i32
static const size_t OFF_DEGL  = OFF_CURN  + 10240*4;                  // E_EDGE i32
static const size_t OFF_CURL  = OFF_DEGL  + (size_t)E_EDGE*4;         // E_EDGE i32
static const size_t ZERO_BYTES= OFF_CURL  + (size_t)E_EDGE*4;
// non-zeroed:
static const size_t OFF_CONST = ZERO_BYTES;                           // 512 f32 (Ball 432 + cvec 24)
static const size_t OFF_V0    = OFF_CONST + 512*4;                    // [E,6]  f32
static const size_t OFF_V12   = OFF_V0    + (size_t)E_EDGE*6*4;       // [E,16] f32 (12 used, 64B rows)
static const size_t OFF_PW    = OFF_V12   + (size_t)E_EDGE*16*4;      // [E,16] f32 (12 PW + wsum@12)
static const size_t OFF_STARTN= OFF_PW    + (size_t)E_EDGE*16*4;      // 10304 i32 (uses 10001)
static const size_t OFF_SRCSN = OFF_STARTN+ 10304*4;                  // [E] i32 (CSR-sorted src node)
static const size_t OFF_POSN  = OFF_SRCSN + (size_t)E_EDGE*4;         // [E] i32 (edge -> CSR slot)
static const size_t OFF_WKS4  = OFF_POSN  + (size_t)E_EDGE*4;         // [E] float4 (w0,w1,w2,0) CSR-sorted
static const size_t OFF_STARTL= OFF_WKS4  + (size_t)E_EDGE*16;        // E_EDGE+64 i32
static const size_t OFF_LSW   = OFF_STARTL+ ((size_t)E_EDGE+64)*4;    // [E_LINK] int2 (src, w-bits), sorted
static const size_t OFF_HENT  = OFF_LSW   + (size_t)E_LINKN*8;        // [N,128]
static const size_t OFF_HA    = OFF_HENT  + (size_t)N_NODE*DIM*4;     // [N,128]
static const size_t OFF_HB    = OFF_HA    + (size_t)N_NODE*DIM*4;     // [N,128]
static const size_t OFF_HC    = OFF_HB    + (size_t)N_NODE*DIM*4;     // [N,128]
static const size_t OFF_PARTN = OFF_HC    + (size_t)N_NODE*DIM*4;     // 512 i32 (partials+offs, node)
static const size_t OFF_PARTL = OFF_PARTN + 512*4;                    // 512 i32 (partials+offs, link)

// ---------------- tiny-constant precompute ----------------
__global__ void consts_kernel(const float* __restrict__ Wstart, const float* __restrict__ bstart,
                              const float* __restrict__ Whl,    const float* __restrict__ bhl,
                              const float* __restrict__ Wec,    const float* __restrict__ bec,
                              float* __restrict__ Ball, float* __restrict__ cvec) {
    __shared__ float M[128*129];   // 66048 B
    __shared__ float sWec[768];
    __shared__ float A[768];       // A[r*6 + j] for this block's k
    int k = blockIdx.x;
    int t = threadIdx.x;

    for (int i = t; i < 768; i += 256) sWec[i] = Wec[i];

    const float* w0 = Whl;
    const float* w1 = Whl + 16384;
    const float* w2 = Whl + 32768;
    for (int idx = t; idx < 16384; idx += 256) {
        int r = idx >> 7, d = idx & 127;
        float m;
        if (k == 0)      m = w0[idx] + w1[idx] + w2[idx];
        else if (k == 1) m = -(w1[idx] + 2.f*w2[idx]);
        else             m = 0.5f * w2[idx];
        M[r*129 + d] = m;
    }
    __syncthreads();

    for (int idx = t; idx < 768; idx += 256) {
        int r = idx / 6, j = idx % 6;
        float s = 0.f;
        for (int d = 0; d < 128; d++) s += M[r*129 + d] * sWec[d*6 + j];
        A[idx] = s;
    }
    __syncthreads();

    if (t < 144) {
        int i = t / 6, j = t % 6;
        float s = 0.f;
        for (int r = 0; r < 128; r++) s += Wstart[i*128 + r] * A[r*6 + j];
        Ball[i*18 + k*6 + j] = s;
    } else if (t < 150) {
        int j = t - 144;
        float s = 0.f;
        for (int r = 0; r < 128; r++) s += bstart[r] * A[r*6 + j];
        cvec[k*6 + j] = s;
    } else if (k == 0 && t >= 160 && t < 166) {
        int j = t - 160;
        float s = bec[j];
        for (int d = 0; d < 128; d++) s += bhl[d] * sWec[d*6 + j];
        cvec[18 + j] = s;
    }
}

// V = x_link @ Ball : V0 = cols 0..5 (stride 6), V12 = cols 6..17 (stride 16, 64B rows)
__global__ void v_kernel(const float* __restrict__ x, const float* __restrict__ Ball,
                         float* __restrict__ V0, float* __restrict__ V12) {
    __shared__ float sB[432];
    for (int i = threadIdx.x; i < 432; i += blockDim.x) sB[i] = Ball[i];
    __syncthreads();
    int e = blockIdx.x * blockDim.x + threadIdx.x;
    if (e >= E_EDGE) return;
    float xr[24];
    const float4* xp = (const float4*)(x + (size_t)e*24);
#pragma unroll
    for (int q = 0; q < 6; q++) {
        float4 v = xp[q];
        xr[4*q+0] = v.x; xr[4*q+1] = v.y; xr[4*q+2] = v.z; xr[4*q+3] = v.w;
    }
    float o[18];
#pragma unroll
    for (int j = 0; j < 18; j++) o[j] = 0.f;
#pragma unroll
    for (int i = 0; i < 24; i++) {
        float xv = xr[i];
#pragma unroll
        for (int j = 0; j < 18; j++) o[j] += xv * sB[i*18 + j];
    }
    float2* v0p = (float2*)(V0 + (size_t)e*6);
    v0p[0] = make_float2(o[0], o[1]);
    v0p[1] = make_float2(o[2], o[3]);
    v0p[2] = make_float2(o[4], o[5]);
    float4* v12p = (float4*)(V12 + (size_t)e*16);
    v12p[0] = make_float4(o[6],  o[7],  o[8],  o[9]);
    v12p[1] = make_float4(o[10], o[11], o[12], o[13]);
    v12p[2] = make_float4(o[14], o[15], o[16], o[17]);
}

// ---------------- CSR builds ----------------
__global__ void hist_kernel(const int* __restrict__ dst, int* __restrict__ deg, int n) {
    int e = blockIdx.x * blockDim.x + threadIdx.x;
    if (e < n) atomicAdd(deg + dst[e], 1);
}

__global__ void partial_kernel(const int* __restrict__ deg, int* __restrict__ partials, int n) {
    __shared__ int red[256];
    int b = blockIdx.x, t = threadIdx.x;
    int base = b * SCAN_CHUNK;
    int s = 0;
    for (int i = t; i < SCAN_CHUNK; i += 256) {
        int idx = base + i;
        if (idx < n) s += deg[idx];
    }
    red[t] = s;
    __syncthreads();
    for (int off = 128; off > 0; off >>= 1) {
        if (t < off) red[t] += red[t + off];
        __syncthreads();
    }
    if (t == 0) partials[b] = red[0];
}

__global__ void scan_partials_kernel(const int* __restrict__ partials, int* __restrict__ offs,
                                     int* __restrict__ start, int nb, int n) {
    __shared__ int a[256];
    int t = threadIdx.x;
    a[t] = (t < nb) ? partials[t] : 0;
    __syncthreads();
    for (int off = 1; off < 256; off <<= 1) {
        int v = (t >= off) ? a[t - off] : 0;
        __syncthreads();
        a[t] += v;
        __syncthreads();
    }
    offs[t] = (t == 0) ? 0 : a[t - 1];
    if (t == 255) start[n] = a[nb - 1];
}

__global__ void scan_block_kernel(const int* __restrict__ deg, const int* __restrict__ offs,
                                  int* __restrict__ start, int n) {
    __shared__ int s[SCAN_CHUNK];
    __shared__ int tsum[256];
    int b = blockIdx.x, t = threadIdx.x;
    int base = b * SCAN_CHUNK;
    for (int i = t; i < SCAN_CHUNK; i += 256) {
        int idx = base + i;
        s[i] = (idx < n) ? deg[idx] : 0;
    }
    __syncthreads();
    int lo = t * 16;
    int mysum = 0;
#pragma unroll
    for (int j = 0; j < 16; j++) mysum += s[lo + j];
    tsum[t] = mysum;
    __syncthreads();
    for (int off = 1; off < 256; off <<= 1) {
        int v = (t >= off) ? tsum[t - off] : 0;
        __syncthreads();
        tsum[t] += v;
        __syncthreads();
    }
    int run = offs[b] + ((t == 0) ? 0 : tsum[t - 1]);
#pragma unroll
    for (int j = 0; j < 16; j++) {
        int v = s[lo + j];
        s[lo + j] = run;
        run += v;
    }
    __syncthreads();
    for (int i = t; i < SCAN_CHUNK; i += 256) {
        int idx = base + i;
        if (idx < n) start[idx] = s[i];
    }
}

// node-graph fill: store sorted src and edge->slot map (wks4 gets written sorted later)
__global__ void fill_n_kernel(const int* __restrict__ srcn, const int* __restrict__ dstn,
                              const int* __restrict__ start, int* __restrict__ cursor,
                              int* __restrict__ srcs_srt, int* __restrict__ pos) {
    int e = blockIdx.x * blockDim.x + threadIdx.x;
    if (e >= E_EDGE) return;
    int d = dstn[e];
    int p = start[d] + atomicAdd(cursor + d, 1);
    srcs_srt[p] = srcn[e];
    pos[e] = p;
}

// link-graph fill: packed (src, w-bits) int2 in CSR order — one 8B store
__global__ void fill_l_kernel(const int* __restrict__ srcl, const int* __restrict__ dstl,
                              const float* __restrict__ ew,
                              const int* __restrict__ start, int* __restrict__ cursor,
                              int2* __restrict__ lsw) {
    int e = blockIdx.x * blockDim.x + threadIdx.x;
    if (e >= E_LINKN) return;
    int d = dstl[e];
    int p = start[d] + atomicAdd(cursor + d, 1);
    lsw[p] = make_int2(srcl[e], __float_as_int(ew[e]));
}

// PW[e,0:12] = sum_links w*V12[src], PW[e,12] = sum w   (pure gather, 1 cacheline/neighbor)
__global__ void prop1_gather(const float* __restrict__ V12, const int* __restrict__ startl,
                             const int2* __restrict__ lsw, float* __restrict__ PW) {
    int e = blockIdx.x * blockDim.x + threadIdx.x;
    if (e >= E_EDGE) return;
    int s0 = startl[e], s1 = startl[e + 1];
    float acc[12];
#pragma unroll
    for (int j = 0; j < 12; j++) acc[j] = 0.f;
    float ws = 0.f;
    int2 cur = make_int2(0, 0);
    if (s0 < s1) cur = lsw[s0];
    for (int j = s0; j < s1; j++) {
        int2 nxt = (j + 1 < s1) ? lsw[j + 1] : cur;
        float w = __int_as_float(cur.y);
        const float4* vp = (const float4*)(V12 + (size_t)cur.x*16);
#pragma unroll
        for (int q = 0; q < 3; q++) {
            float4 v = vp[q];
            acc[4*q+0] += w*v.x; acc[4*q+1] += w*v.y;
            acc[4*q+2] += w*v.z; acc[4*q+3] += w*v.w;
        }
        ws += w;
        cur = nxt;
    }
    float4* pw = (float4*)(PW + (size_t)e*16);
    pw[0] = make_float4(acc[0], acc[1], acc[2],  acc[3]);
    pw[1] = make_float4(acc[4], acc[5], acc[6],  acc[7]);
    pw[2] = make_float4(acc[8], acc[9], acc[10], acc[11]);
    pw[3] = make_float4(ws, 0.f, 0.f, 0.f);
}

// fused: gather P2/wsum2 (one cacheline per neighbor), combine, sigmoid -> wks4 (one 16B store)
__global__ void prop2score_kernel(const float* __restrict__ PW,
                                  const int* __restrict__ startl, const int2* __restrict__ lsw,
                                  const float* __restrict__ V0,
                                  const float* __restrict__ cvec, const int* __restrict__ posn,
                                  float4* __restrict__ wks4) {
    __shared__ float sc[24];
    if (threadIdx.x < 24) sc[threadIdx.x] = cvec[threadIdx.x];
    __syncthreads();
    int e = blockIdx.x * blockDim.x + threadIdx.x;
    if (e >= E_EDGE) return;
    int s0 = startl[e], s1 = startl[e + 1];
    float p2[6];
#pragma unroll
    for (int j = 0; j < 6; j++) p2[j] = 0.f;
    float ws2 = 0.f;
    int2 cur = make_int2(0, 0);
    if (s0 < s1) cur = lsw[s0];
    for (int j = s0; j < s1; j++) {
        int2 nxt = (j + 1 < s1) ? lsw[j + 1] : cur;
        float w = __int_as_float(cur.y);
        const float4* pv = (const float4*)(PW + (size_t)cur.x*16);
        float4 a = pv[1];   // cols 4..7 (use z,w = cols 6,7)
        float4 b = pv[2];   // cols 8..11
        float4 c = pv[3];   // col 12 = wsum in .x
        p2[0] += w*a.z; p2[1] += w*a.w;
        p2[2] += w*b.x; p2[3] += w*b.y; p2[4] += w*b.z; p2[5] += w*b.w;
        ws2 += w * c.x;
        cur = nxt;
    }
    const float4* pe = (const float4*)(PW + (size_t)e*16);
    float4 q0 = pe[0];                 // cols 0..3
    float4 q1 = pe[1];                 // cols 4..7 (use x,y)
    float  ws1 = pe[3].x;              // col 12
    float pw6[6] = {q0.x, q0.y, q0.z, q0.w, q1.x, q1.y};
    const float2* v0p = (const float2*)(V0 + (size_t)e*6);
    float2 f0 = v0p[0], f1 = v0p[1], f2 = v0p[2];
    float v0r[6] = {f0.x, f0.y, f1.x, f1.y, f2.x, f2.y};
    float S[6];
#pragma unroll
    for (int j = 0; j < 6; j++)
        S[j] = v0r[j] + pw6[j] + p2[j]
             + ws1*sc[6 + j] + ws2*sc[12 + j] + sc[j] + sc[18 + j];
    int p = posn[e];
    float w0 = 1.f / (1.f + __expf(S[1] - S[0]));
    float w1 = 1.f / (1.f + __expf(S[3] - S[2]));
    float w2 = 1.f / (1.f + __expf(S[5] - S[4]));
    wks4[p] = make_float4(w0, w1, w2, 0.f);
}

// ---------------- temporal projection ----------------
__global__ void temporal_kernel(const float4* __restrict__ h_entity, const float* __restrict__ Wt,
                                const float* __restrict__ bt, float4* __restrict__ h_ent) {
    __shared__ float sw[SEQLEN];
    if (threadIdx.x < SEQLEN) sw[threadIdx.x] = Wt[threadIdx.x];
    __syncthreads();
    int i = blockIdx.x * blockDim.x + threadIdx.x;            // over N*D/4 = 320000
    if (i >= N_NODE*DIM/4) return;
    float b = bt[0];
    float4 acc = make_float4(b, b, b, b);
#pragma unroll 8
    for (int t = 0; t < SEQLEN; t++) {
        float4 v = h_entity[(size_t)t * (N_NODE*DIM/4) + i];
        float w = sw[t];
        acc.x += w*v.x; acc.y += w*v.y; acc.z += w*v.z; acc.w += w*v.w;
    }
    h_ent[i] = acc;
}

// ---------------- GCN hop propagate only: h_next[node] = sum_j w_k[j] * h_cur[src[j]]
__global__ void prop_hop(const float* __restrict__ h_cur, float* __restrict__ h_next,
                         const int* __restrict__ startn, const int* __restrict__ srcs_srt,
                         const float4* __restrict__ wks4, int k) {
    int node = blockIdx.x;
    int tid  = threadIdx.x;          // 128
    int s0 = startn[node], s1 = startn[node + 1];
    float acc = 0.f;
    for (int j = s0; j < s1; j++) {
        float4 wv = wks4[j];
        float w = (k == 0) ? wv.x : (k == 1) ? wv.y : wv.z;
        int sn = srcs_srt[j];
        acc += w * h_cur[(size_t)sn*DIM + tid];
    }
    h_next[(size_t)node*DIM + tid] = acc;
}

// ---------------- fused final GEMM: out = b + h1@G1 + h2@G2 + h3@G3
// 256 thr: cg=t&31 (4 cols), rg=t>>5 (4 rows of 32/block). G_k staged in 64KB LDS.
__global__ void __launch_bounds__(256)
gemm_final(const float* __restrict__ h1, const float* __restrict__ h2,
           const float* __restrict__ h3, const float* __restrict__ Wgcn,
           const float* __restrict__ bgcn, float* __restrict__ out) {
    __shared__ float sG[128*128];   // 64 KB
    __shared__ float sh[32*128];    // 16 KB
    int t = threadIdx.x;
    int cg = t & 31, rg = t >> 5;
    int c0 = cg * 4, r0 = rg * 4;
    int rbase = blockIdx.x * 32;
    int nrows = N_NODE - rbase; if (nrows > 32) nrows = 32;

    float4 bb = *(const float4*)(bgcn + c0);
    float acc[4][4];
#pragma unroll
    for (int r = 0; r < 4; r++) {
        acc[r][0] = bb.x; acc[r][1] = bb.y; acc[r][2] = bb.z; acc[r][3] = bb.w;
    }

    const float* hs0[3] = {h1, h2, h3};
    for (int k = 0; k < 3; k++) {
        __syncthreads();
        const float4* gk = (const float4*)(Wgcn + (size_t)k*16384);
        float4* sg4 = (float4*)sG;
        for (int i = t; i < 4096; i += 256) sg4[i] = gk[i];
        const float4* hg = (const float4*)(hs0[k] + (size_t)rbase*128);
        float4* sh4 = (float4*)sh;
        for (int i = t; i < 1024; i += 256)
            sh4[i] = ((i >> 5) < nrows) ? hg[i] : make_float4(0.f, 0.f, 0.f, 0.f);
        __syncthreads();
#pragma unroll 2
        for (int d4 = 0; d4 < 32; d4++) {
            float4 g0 = *(const float4*)(sG + (d4*4 + 0)*128 + c0);
            float4 g1 = *(const float4*)(sG + (d4*4 + 1)*128 + c0);
            float4 g2 = *(const float4*)(sG + (d4*4 + 2)*128 + c0);
            float4 g3 = *(const float4*)(sG + (d4*4 + 3)*128 + c0);
#pragma unroll
            for (int r = 0; r < 4; r++) {
                float4 hv = *(const float4*)(sh + (r0 + r)*128 + d4*4);
                acc[r][0] += hv.x*g0.x; acc[r][1] += hv.x*g0.y; acc[r][2] += hv.x*g0.z; acc[r][3] += hv.x*g0.w;
                acc[r][0] += hv.y*g1.x; acc[r][1] += hv.y*g1.y; acc[r][2] += hv.y*g1.z; acc[r][3] += hv.y*g1.w;
                acc[r][0] += hv.z*g2.x; acc[r][1] += hv.z*g2.y; acc[r][2] += hv.z*g2.z; acc[r][3] += hv.z*g2.w;
                acc[r][0] += hv.w*g3.x; acc[r][1] += hv.w*g3.y; acc[r][2] += hv.w*g3.z; acc[r][3] += hv.w*g3.w;
            }
        }
    }
#pragma unroll
    for (int r = 0; r < 4; r++) {
        if (r0 + r < nrows)
            *(float4*)(out + (size_t)(rbase + r0 + r)*128 + c0) =
                make_float4(acc[r][0], acc[r][1], acc[r][2], acc[r][3]);
    }
}

extern "C" void kernel_launch(void* const* d_in, const int* in_sizes, int n_in,
                              void* d_out, int out_size, void* d_ws, size_t ws_size,
                              hipStream_t stream) {
    const float* h_entity = (const float*)d_in[0];
    const float* x_link   = (const float*)d_in[1];
    const float* ewl      = (const float*)d_in[2];
    const int*   eil      = (const int*)d_in[3];
    const int*   ein      = (const int*)d_in[4];
    const float* Wstart   = (const float*)d_in[5];
    const float* bstart   = (const float*)d_in[6];
    const float* Whl      = (const float*)d_in[7];
    const float* bhl      = (const float*)d_in[8];
    const float* Wec      = (const float*)d_in[9];
    const float* bec      = (const float*)d_in[10];
    const float* Wt       = (const float*)d_in[11];
    const float* bt       = (const float*)d_in[12];
    const float* Wgcn     = (const float*)d_in[13];
    const float* bgcn     = (const float*)d_in[14];
    float* out = (float*)d_out;
    char*  ws  = (char*)d_ws;

    const int* srcl = eil;
    const int* dstl = eil + E_LINKN;
    const int* srcn = ein;
    const int* dstn = ein + E_EDGE;

    int*    degn  = (int*)   (ws + OFF_DEGN);
    int*    curn  = (int*)   (ws + OFF_CURN);
    int*    degl  = (int*)   (ws + OFF_DEGL);
    int*    curl  = (int*)   (ws + OFF_CURL);
    float*  Ball  = (float*) (ws + OFF_CONST);
    float*  cvec  = Ball + 432;
    float*  V0    = (float*) (ws + OFF_V0);
    float*  V12   = (float*) (ws + OFF_V12);
    float*  PW    = (float*) (ws + OFF_PW);
    int*    startn= (int*)   (ws + OFF_STARTN);
    int*    srcsn = (int*)   (ws + OFF_SRCSN);
    int*    posn  = (int*)   (ws + OFF_POSN);
    float4* wks4  = (float4*)(ws + OFF_WKS4);
    int*    startl= (int*)   (ws + OFF_STARTL);
    int2*   lsw   = (int2*)  (ws + OFF_LSW);
    float*  h_ent = (float*) (ws + OFF_HENT);
    float*  h_a   = (float*) (ws + OFF_HA);
    float*  h_b   = (float*) (ws + OFF_HB);
    float*  h_c   = (float*) (ws + OFF_HC);
    int*    partn = (int*)   (ws + OFF_PARTN);  // partials, offs = partn+256
    int*    partl = (int*)   (ws + OFF_PARTL);

    const int nbN = (N_NODE + SCAN_CHUNK - 1) / SCAN_CHUNK;   // 3
    const int nbL = (E_EDGE + SCAN_CHUNK - 1) / SCAN_CHUNK;   // 79

    hipMemsetAsync(ws, 0, ZERO_BYTES, stream);

    consts_kernel<<<3, 256, 0, stream>>>(Wstart, bstart, Whl, bhl, Wec, bec, Ball, cvec);
    v_kernel<<<(E_EDGE + 255)/256, 256, 0, stream>>>(x_link, Ball, V0, V12);

    // CSR builds (hist -> hierarchical scan -> fill)
    hist_kernel<<<(E_EDGE + 255)/256, 256, 0, stream>>>(dstn, degn, E_EDGE);
    hist_kernel<<<(E_LINKN + 255)/256, 256, 0, stream>>>(dstl, degl, E_LINKN);

    partial_kernel<<<nbN, 256, 0, stream>>>(degn, partn, N_NODE);
    scan_partials_kernel<<<1, 256, 0, stream>>>(partn, partn + 256, startn, nbN, N_NODE);
    scan_block_kernel<<<nbN, 256, 0, stream>>>(degn, partn + 256, startn, N_NODE);

    partial_kernel<<<nbL, 256, 0, stream>>>(degl, partl, E_EDGE);
    scan_partials_kernel<<<1, 256, 0, stream>>>(partl, partl + 256, startl, nbL, E_EDGE);
    scan_block_kernel<<<nbL, 256, 0, stream>>>(degl, partl + 256, startl, E_EDGE);

    fill_n_kernel<<<(E_EDGE + 255)/256, 256, 0, stream>>>(srcn, dstn, startn, curn, srcsn, posn);
    fill_l_kernel<<<(E_LINKN + 255)/256, 256, 0, stream>>>(srcl, dstl, ewl, startl, curl, lsw);

    // link-graph propagates (gather, 1 cacheline per neighbor)
    prop1_gather<<<(E_EDGE + 255)/256, 256, 0, stream>>>(V12, startl, lsw, PW);
    prop2score_kernel<<<(E_EDGE + 255)/256, 256, 0, stream>>>(PW, startl, lsw, V0, cvec,
                                                              posn, wks4);

    temporal_kernel<<<(N_NODE*DIM/4 + 255)/256, 256, 0, stream>>>(
        (const float4*)h_entity, Wt, bt, (float4*)h_ent);

    // 3 gather hops, then one LDS-tiled GEMM for all three projections
    prop_hop<<<N_NODE, DIM, 0, stream>>>(h_ent, h_a, startn, srcsn, wks4, 0);
    prop_hop<<<N_NODE, DIM, 0, stream>>>(h_a,   h_b, startn, srcsn, wks4, 1);
    prop_hop<<<N_NODE, DIM, 0, stream>>>(h_b,   h_c, startn, srcsn, wks4, 2);

    gemm_final<<<(N_NODE + 31)/32, 256, 0, stream>>>(h_a, h_b, h_c, Wgcn, bgcn, out);
}